// Round 5
// baseline (273.585 us; speedup 1.0000x reference)
//
#include <hip/hip_runtime.h>

#define BIG 3.0e38f

// ---------------------------------------------------------------------------
// Partial KNN (k=3) over one chunk of the candidate set.
// Block = 256 queries x CHUNK candidates (chunk = blockIdx.y, nC = gridDim.y).
// ---------------------------------------------------------------------------
template <int CHUNK>
__global__ __launch_bounds__(256) void knn_partial(const float* __restrict__ xyzF,
                                                   const float* __restrict__ xyzC,
                                                   int N,
                                                   float* __restrict__ pd,
                                                   int* __restrict__ pi) {
    __shared__ float4 sc[CHUNK];
    const int b = blockIdx.z;
    const int ch = blockIdx.y;
    const int nC = gridDim.y;
    const int tid = threadIdx.x;
    const int S = nC * CHUNK;
    const int base = ch * CHUNK;

    for (int i = tid; i < CHUNK; i += 256) {
        const float x = xyzC[(b * S + base + i) * 3 + 0];
        const float y = xyzC[(b * S + base + i) * 3 + 1];
        const float z = xyzC[(b * S + base + i) * 3 + 2];
        sc[i] = make_float4(x, y, z, x * x + y * y + z * z);
    }
    __syncthreads();

    const int n = blockIdx.x * 256 + tid;
    const float ax = xyzF[(b * N + n) * 3 + 0];
    const float ay = xyzF[(b * N + n) * 3 + 1];
    const float az = xyzF[(b * N + n) * 3 + 2];
    const float an = ax * ax + ay * ay + az * az;

    float d0 = BIG, d1 = BIG, d2 = BIG;
    int i0 = 0, i1 = 0, i2 = 0;

#pragma unroll 4
    for (int s = 0; s < CHUNK; ++s) {
        const float4 p = sc[s];
        const float t = ax * p.x + ay * p.y + az * p.z;
        const float d = an + p.w - 2.0f * t;  // matches ref formula exactly
        if (d < d2) {
            if (d < d1) {
                if (d < d0) {
                    d2 = d1; i2 = i1;
                    d1 = d0; i1 = i0;
                    d0 = d;  i0 = base + s;
                } else {
                    d2 = d1; i2 = i1;
                    d1 = d;  i1 = base + s;
                }
            } else {
                d2 = d; i2 = base + s;
            }
        }
    }

    const size_t o = ((size_t)(b * nC + ch) * 3) * N + n;
    pd[o + 0 * N] = d0;  pi[o + 0 * N] = i0;
    pd[o + 1 * N] = d1;  pi[o + 1 * N] = i1;
    pd[o + 2 * N] = d2;  pi[o + 2 * N] = i2;
}

// ---------------------------------------------------------------------------
// Merge nC partial top-3 lists -> final top-3 + inverse-distance weights.
// Chunk-order insertion with strict < preserves earliest-index ties.
// ---------------------------------------------------------------------------
__global__ __launch_bounds__(64) void knn_merge(const float* __restrict__ pd,
                                                const int* __restrict__ pi,
                                                int N, int nC,
                                                int* __restrict__ idx,
                                                float* __restrict__ w) {
    const int b = blockIdx.y;
    const int n = blockIdx.x * 64 + threadIdx.x;

    float d0 = BIG, d1 = BIG, d2 = BIG;
    int i0 = 0, i1 = 0, i2 = 0;

    for (int ch = 0; ch < nC; ++ch) {
        const size_t o = ((size_t)(b * nC + ch) * 3) * N + n;
#pragma unroll
        for (int k = 0; k < 3; ++k) {
            const float d = pd[o + (size_t)k * N];
            const int ii = pi[o + (size_t)k * N];
            if (d < d2) {
                if (d < d1) {
                    if (d < d0) {
                        d2 = d1; i2 = i1;
                        d1 = d0; i1 = i0;
                        d0 = d;  i0 = ii;
                    } else {
                        d2 = d1; i2 = i1;
                        d1 = d;  i1 = ii;
                    }
                } else {
                    d2 = d; i2 = ii;
                }
            }
        }
    }

    const float r0 = 1.0f / (d0 + 1e-8f);
    const float r1 = 1.0f / (d1 + 1e-8f);
    const float r2 = 1.0f / (d2 + 1e-8f);
    const float rs = r0 + r1 + r2;

    idx[(b * 3 + 0) * N + n] = i0;
    idx[(b * 3 + 1) * N + n] = i1;
    idx[(b * 3 + 2) * N + n] = i2;
    w[(b * 3 + 0) * N + n] = r0 / rs;
    w[(b * 3 + 1) * N + n] = r1 / rs;
    w[(b * 3 + 2) * N + n] = r2 / rs;
}

// ---------------------------------------------------------------------------
// Channel-major [B,C,N] -> point-major out[b][n][co + c] (row stride OS).
// ---------------------------------------------------------------------------
__global__ __launch_bounds__(256) void transpose_pm(const float* __restrict__ in,
                                                    float* __restrict__ out,
                                                    int C, int N, int OS, int co) {
    __shared__ float s[64][65];
    const int b = blockIdx.z;
    const int nb = blockIdx.x * 64;
    const int cb = blockIdx.y * 64;
    const int lo = threadIdx.x & 63;
    const int r  = threadIdx.x >> 6;

#pragma unroll
    for (int i = 0; i < 16; ++i) {
        const int cl = r + 4 * i;
        s[cl][lo] = in[((size_t)b * C + cb + cl) * N + nb + lo];
    }
    __syncthreads();
#pragma unroll
    for (int i = 0; i < 16; ++i) {
        const int pl = r + 4 * i;
        out[((size_t)b * N + nb + pl) * OS + co + cb + lo] = s[lo][pl];
    }
}

// ---------------------------------------------------------------------------
// Stage-1 interp, point-major, float4 gathers, batch-partitioned XCD swizzle.
// 1024 blocks: xcd=id&7 -> b=xcd>>1, nhalf=xcd&1; q=id>>3 -> ntsub=q&15,
// ctile=q>>4 (ctile slowest => per-XCD hot x2P slice stays in L2).
// Thread: point p = tid>>2, quarter qd = tid&3 (4 float4 per point-quarter).
// ---------------------------------------------------------------------------
__global__ __launch_bounds__(256) void interp1(const float* __restrict__ x2P,
                                               const int* __restrict__ idx,
                                               const float* __restrict__ w,
                                               float* __restrict__ featP) {
    __shared__ int   sj[3][64];
    __shared__ float sw[3][64];
    const int id = blockIdx.x;
    const int xcd = id & 7;
    const int b = xcd >> 1;
    const int q = id >> 3;
    const int ntile = (xcd & 1) * 16 + (q & 15);   // 0..31
    const int cb = (q >> 4) * 64;                  // 0..511 step 64
    const int nb = ntile * 64;
    const int tid = threadIdx.x;

    if (tid < 64) {
#pragma unroll
        for (int k = 0; k < 3; ++k) {
            sj[k][tid] = idx[(b * 3 + k) * 2048 + nb + tid];
            sw[k][tid] = w[(b * 3 + k) * 2048 + nb + tid];
        }
    }
    __syncthreads();

    const int p = tid >> 2, qd = tid & 3;
    const float4* r0 = (const float4*)(x2P + ((size_t)b * 512 + sj[0][p]) * 512 + cb);
    const float4* r1 = (const float4*)(x2P + ((size_t)b * 512 + sj[1][p]) * 512 + cb);
    const float4* r2 = (const float4*)(x2P + ((size_t)b * 512 + sj[2][p]) * 512 + cb);
    const float w0 = sw[0][p], w1 = sw[1][p], w2 = sw[2][p];
    float4* dst = (float4*)(featP + ((size_t)b * 2048 + nb + p) * 768 + 256 + cb);

#pragma unroll
    for (int j = 0; j < 4; ++j) {
        const int c4 = qd + 4 * j;
        const float4 a = r0[c4], bb = r1[c4], cc = r2[c4];
        float4 v;
        v.x = w0 * a.x + w1 * bb.x + w2 * cc.x;
        v.y = w0 * a.y + w1 * bb.y + w2 * cc.y;
        v.z = w0 * a.z + w1 * bb.z + w2 * cc.z;
        v.w = w0 * a.w + w1 * bb.w + w2 * cc.w;
        dst[c4] = v;
    }
}

// ---------------------------------------------------------------------------
// Final interp: out[b][128+c][n] = sum_k w_k * featP[b][j_k][c].
// 6144 blocks: xcd=id&7 -> b=xcd>>1, nhalf=xcd&1; q=id>>3 -> ntsub=q&63,
// ctile=q>>6 (slowest). Per (XCD,ctile) hot featP slice = 2048x256B = 512 KB
// -> L2-resident; featP HBM fetch ~48 MB instead of ~300 MB.
// float4 gathers; LDS tile transpose for coalesced channel-major writes.
// ---------------------------------------------------------------------------
__global__ __launch_bounds__(256) void final_interp(const float* __restrict__ featP,
                                                    const int* __restrict__ idx,
                                                    const float* __restrict__ w,
                                                    float* __restrict__ out) {
    __shared__ float tile[64][65];
    __shared__ int   sj[3][64];
    __shared__ float sw[3][64];
    const int id = blockIdx.x;
    const int xcd = id & 7;
    const int b = xcd >> 1;
    const int q = id >> 3;
    const int ntile = (xcd & 1) * 64 + (q & 63);   // 0..127
    const int cb = (q >> 6) * 64;                  // 0..767 step 64
    const int nb = ntile * 64;
    const int tid = threadIdx.x;

    if (tid < 64) {
#pragma unroll
        for (int k = 0; k < 3; ++k) {
            sj[k][tid] = idx[(b * 3 + k) * 8192 + nb + tid];
            sw[k][tid] = w[(b * 3 + k) * 8192 + nb + tid];
        }
    }
    __syncthreads();

    {
        const int p = tid >> 2, qd = tid & 3;
        const float4* r0 = (const float4*)(featP + ((size_t)b * 2048 + sj[0][p]) * 768 + cb);
        const float4* r1 = (const float4*)(featP + ((size_t)b * 2048 + sj[1][p]) * 768 + cb);
        const float4* r2 = (const float4*)(featP + ((size_t)b * 2048 + sj[2][p]) * 768 + cb);
        const float w0 = sw[0][p], w1 = sw[1][p], w2 = sw[2][p];
#pragma unroll
        for (int j = 0; j < 4; ++j) {
            const int c4 = qd + 4 * j;
            const float4 a = r0[c4], bb = r1[c4], cc = r2[c4];
            tile[p][c4 * 4 + 0] = w0 * a.x + w1 * bb.x + w2 * cc.x;
            tile[p][c4 * 4 + 1] = w0 * a.y + w1 * bb.y + w2 * cc.y;
            tile[p][c4 * 4 + 2] = w0 * a.z + w1 * bb.z + w2 * cc.z;
            tile[p][c4 * 4 + 3] = w0 * a.w + w1 * bb.w + w2 * cc.w;
        }
    }
    __syncthreads();
    {
        const int n4 = tid & 15;         // float4 index along n
        const int clb = tid >> 4;        // 0..15
#pragma unroll
        for (int i = 0; i < 4; ++i) {
            const int cl = clb + 16 * i;
            float4 v;
            v.x = tile[n4 * 4 + 0][cl];
            v.y = tile[n4 * 4 + 1][cl];
            v.z = tile[n4 * 4 + 2][cl];
            v.w = tile[n4 * 4 + 3][cl];
            *(float4*)(out + ((size_t)b * 896 + 128 + cb + cl) * 8192 + nb + n4 * 4) = v;
        }
    }
}

// ---------------------------------------------------------------------------
// out channels 0..127 = x0 (contiguous per batch), float4 copy.
// ---------------------------------------------------------------------------
__global__ __launch_bounds__(256) void copy_x0(const float4* __restrict__ x0,
                                               float4* __restrict__ out) {
    const int b = blockIdx.y;
    const int i = blockIdx.x * 256 + threadIdx.x;          // 0..262143
    out[(size_t)b * (896 * 2048) + i] = x0[(size_t)b * (128 * 2048) + i];
}

extern "C" void kernel_launch(void* const* d_in, const int* in_sizes, int n_in,
                              void* d_out, int out_size, void* d_ws, size_t ws_size,
                              hipStream_t stream) {
    const float* xyz0 = (const float*)d_in[0];  // [4,8192,3]
    const float* xyz1 = (const float*)d_in[1];  // [4,2048,3]
    const float* xyz2 = (const float*)d_in[2];  // [4,512,3]
    const float* x0   = (const float*)d_in[3];  // [4,128,8192]
    const float* x1   = (const float*)d_in[4];  // [4,256,2048]
    const float* x2   = (const float*)d_in[5];  // [4,512,512]
    float* out = (float*)d_out;                 // [4,896,8192]

    // Workspace layout (bytes):
    //   featP : float[4*2048*768]  @ 0          (25,165,824)
    //   idx1  : int  [4*3*2048]    @ 25,165,824 (98,304)
    //   w1    : float[4*3*2048]    @ 25,264,128 (98,304)
    //   idx2  : int  [4*3*8192]    @ 25,362,432 (393,216)
    //   w2    : float[4*3*8192]    @ 25,755,648 (393,216)
    //   pd    : float[4*16*3*8192] @ 26,148,864 (6,291,456)
    //   pi    : int  [4*16*3*8192] @ 32,440,320 (6,291,456)
    //   x2P   : float[4*512*512]   @ 26,148,864 (4,194,304) aliases pd/pi:
    //     knn1 -> merge1 -> t_x2 (clobbers pd) -> interp1 (reads x2P)
    //     -> knn2 (clobbers x2P) -> merge2 -> final.  Stream order makes it safe.
    char* ws = (char*)d_ws;
    float* featP = (float*)(ws + 0);
    int*   idx1  = (int*)(ws + 25165824);
    float* w1    = (float*)(ws + 25264128);
    int*   idx2  = (int*)(ws + 25362432);
    float* w2    = (float*)(ws + 25755648);
    float* pd    = (float*)(ws + 26148864);
    int*   pi    = (int*)(ws + 32440320);
    float* x2P   = (float*)(ws + 26148864);  // aliases pd (see ordering above)

    // Stage-1 KNN: queries=xyz1 (N=2048), candidates=xyz2 (S=512, 16 chunks of 32)
    knn_partial<32><<<dim3(8, 16, 4), 256, 0, stream>>>(xyz1, xyz2, 2048, pd, pi);
    knn_merge<<<dim3(2048 / 64, 4), 64, 0, stream>>>(pd, pi, 2048, 16, idx1, w1);

    // Point-major staging (t_x2 clobbers pd/pi — dead after merge1)
    transpose_pm<<<dim3(512 / 64, 512 / 64, 4), 256, 0, stream>>>(x2, x2P, 512, 512, 512, 0);
    transpose_pm<<<dim3(2048 / 64, 256 / 64, 4), 256, 0, stream>>>(x1, featP, 256, 2048, 768, 0);
    interp1<<<dim3(1024), 256, 0, stream>>>(x2P, idx1, w1, featP);

    // Stage-2 KNN: queries=xyz0 (N=8192), candidates=xyz1 (S=2048, 16 chunks of 128)
    // (clobbers x2P — dead after interp1)
    knn_partial<128><<<dim3(32, 16, 4), 256, 0, stream>>>(xyz0, xyz1, 8192, pd, pi);
    knn_merge<<<dim3(8192 / 64, 4), 64, 0, stream>>>(pd, pi, 8192, 16, idx2, w2);

    // Output
    copy_x0<<<dim3(1024, 4), 256, 0, stream>>>((const float4*)x0, (float4*)out);
    final_interp<<<dim3(6144), 256, 0, stream>>>(featP, idx2, w2, out);
}